// Round 4
// baseline (44.669 us; speedup 1.0000x reference)
//
#include <hip/hip_runtime.h>
#include <math.h>

// B=4, T=S=512, M=N=512, H=128
#define KDIM 512
#define HDIM 128
#define SDIM 512
#define INV_SCALE 0.04419417382415922f   // 1/sqrt(512)
#define C_OFF 16                          // float index of c' array in ws (counter lives at ws[0])

// score[b,t,s] = a'[b,t] + c'[b,s]   (both pre-scaled by INV_SCALE)
//   a'[b,t] = inv_scale * sum_h v[h]   * tanh(q[b,t,:]·W2[h,:])
//   c'[b,s] = inv_scale * sum_h v[H+h] * tanh(k[b,s,:]·W1[h,:])

__device__ __forceinline__ float fast_tanh(float x) {
    // tanh(x) = 1 - 2/(e^{2x}+1); ~1e-7 abs error, graceful at +/-inf
    float e = __expf(2.0f * x);
    return 1.0f - 2.0f / (e + 1.0f);
}

__global__ __launch_bounds__(256) void fused_kernel(
    const float* __restrict__ query, const float* __restrict__ keys,
    const float* __restrict__ W1, const float* __restrict__ W2,
    const float* __restrict__ v, float* __restrict__ ws,
    float* __restrict__ out)
{
    // blocks [0,256): query rows 8/blk -> keep a' in LDS, then write output tile
    // blocks [256,512): keys rows 8/blk -> store c' to ws (LLC-coherent), arrive, exit
    const int blk = blockIdx.x;
    const bool is_keys = (blk >= 256);
    const float* __restrict__ X  = is_keys ? keys : query;
    const float* __restrict__ W  = is_keys ? W1 : W2;
    const float* __restrict__ vv = v + (is_keys ? HDIM : 0);
    const int row0 = (is_keys ? blk - 256 : blk) * 8;

    __shared__ float sm_x[8][KDIM];   // 16 KB
    __shared__ float sm_p[4][8];      // [wave][r]
    __shared__ float sm_a[8];

    const int tid = threadIdx.x;
    const int ks  = tid & 7;          // K-split slot (lane bits 0-2)
    const int hg  = tid >> 3;         // 32 h-groups of 4 (lane bits 3-5 + wave)

    // Stage X tile: 8*512 floats = 1024 float4; coalesced
    {
        const float4* __restrict__ src = (const float4*)(X + (size_t)row0 * KDIM);
        float4* dst = (float4*)(&sm_x[0][0]);
        #pragma unroll
        for (int i = 0; i < 4; ++i) dst[tid + i * 256] = src[tid + i * 256];
    }
    __syncthreads();

    float acc[8][4];
    #pragma unroll
    for (int r = 0; r < 8; ++r)
        #pragma unroll
        for (int h = 0; h < 4; ++h) acc[r][h] = 0.0f;

    const float* __restrict__ wbase = W + (size_t)(hg * 4) * KDIM;

    // Thread covers K cols {jj*32 + ks*4 .. +3}; per jj: 4 W float4 + 8 LDS b128 + 128 FMA
    #pragma unroll 2
    for (int jj = 0; jj < 16; ++jj) {
        const int col = jj * 32 + ks * 4;
        const float4 w0 = *(const float4*)(wbase + 0 * KDIM + col);
        const float4 w1 = *(const float4*)(wbase + 1 * KDIM + col);
        const float4 w2 = *(const float4*)(wbase + 2 * KDIM + col);
        const float4 w3 = *(const float4*)(wbase + 3 * KDIM + col);
        #pragma unroll
        for (int r = 0; r < 8; ++r) {
            const float4 x = *(const float4*)(&sm_x[r][col]);
            acc[r][0] = fmaf(x.x, w0.x, acc[r][0]);
            acc[r][0] = fmaf(x.y, w0.y, acc[r][0]);
            acc[r][0] = fmaf(x.z, w0.z, acc[r][0]);
            acc[r][0] = fmaf(x.w, w0.w, acc[r][0]);
            acc[r][1] = fmaf(x.x, w1.x, acc[r][1]);
            acc[r][1] = fmaf(x.y, w1.y, acc[r][1]);
            acc[r][1] = fmaf(x.z, w1.z, acc[r][1]);
            acc[r][1] = fmaf(x.w, w1.w, acc[r][1]);
            acc[r][2] = fmaf(x.x, w2.x, acc[r][2]);
            acc[r][2] = fmaf(x.y, w2.y, acc[r][2]);
            acc[r][2] = fmaf(x.z, w2.z, acc[r][2]);
            acc[r][2] = fmaf(x.w, w2.w, acc[r][2]);
            acc[r][3] = fmaf(x.x, w3.x, acc[r][3]);
            acc[r][3] = fmaf(x.y, w3.y, acc[r][3]);
            acc[r][3] = fmaf(x.z, w3.z, acc[r][3]);
            acc[r][3] = fmaf(x.w, w3.w, acc[r][3]);
        }
    }

    // K-split reduce over ks (lane bits 0-2): 32 accs x 3 levels
    #pragma unroll
    for (int r = 0; r < 8; ++r)
        #pragma unroll
        for (int h = 0; h < 4; ++h) {
            float s = acc[r][h];
            s += __shfl_xor(s, 1, 64);
            s += __shfl_xor(s, 2, 64);
            s += __shfl_xor(s, 4, 64);
            acc[r][h] = s;
        }

    const float4 vh = *(const float4*)(vv + hg * 4);
    const int wave = tid >> 6;
    const int lane = tid & 63;

    #pragma unroll
    for (int r = 0; r < 8; ++r) {
        float rs = vh.x * fast_tanh(acc[r][0]) + vh.y * fast_tanh(acc[r][1])
                 + vh.z * fast_tanh(acc[r][2]) + vh.w * fast_tanh(acc[r][3]);
        // reduce over the wave's 8 h-groups (lane bits 3-5)
        rs += __shfl_xor(rs, 8, 64);
        rs += __shfl_xor(rs, 16, 64);
        rs += __shfl_xor(rs, 32, 64);
        if (lane == 0) sm_p[wave][r] = rs;
    }
    __syncthreads();

    if (tid < 8) {
        const float s = (sm_p[0][tid] + sm_p[1][tid] + sm_p[2][tid] + sm_p[3][tid]) * INV_SCALE;
        sm_a[tid] = s;
        if (is_keys)  // publish c' through LLC (coherent across XCDs)
            __hip_atomic_store(&ws[C_OFF + row0 + tid], s,
                               __ATOMIC_RELAXED, __HIP_MEMORY_SCOPE_AGENT);
    }
    __syncthreads();

    unsigned int* ctr = (unsigned int*)ws;
    if (is_keys) {
        if (tid == 0)
            __hip_atomic_fetch_add(ctr, 1u, __ATOMIC_RELEASE, __HIP_MEMORY_SCOPE_AGENT);
        return;
    }

    // query blocks: wait for all 256 keys blocks
    if (tid == 0) {
        while (__hip_atomic_load(ctr, __ATOMIC_ACQUIRE, __HIP_MEMORY_SCOPE_AGENT) < 256u)
            __builtin_amdgcn_s_sleep(1);
    }
    __syncthreads();

    // Phase 2: write rows row0..row0+7; wave w owns rows 2w,2w+1; lane covers s = lane*8..+7
    const int b = row0 >> 9;
    float* cbase = ws + C_OFF + b * SDIM;
    float c[8];
    #pragma unroll
    for (int j = 0; j < 8; ++j)
        c[j] = __hip_atomic_load(&cbase[lane * 8 + j],
                                 __ATOMIC_RELAXED, __HIP_MEMORY_SCOPE_AGENT);
    #pragma unroll
    for (int rr = 0; rr < 2; ++rr) {
        const int r = wave * 2 + rr;
        const float a = sm_a[r];
        float4 o0, o1;
        o0.x = a + c[0]; o0.y = a + c[1]; o0.z = a + c[2]; o0.w = a + c[3];
        o1.x = a + c[4]; o1.y = a + c[5]; o1.z = a + c[6]; o1.w = a + c[7];
        float4* __restrict__ op = (float4*)(out + (size_t)(row0 + r) * SDIM + lane * 8);
        op[0] = o0;
        op[1] = o1;
    }
}

extern "C" void kernel_launch(void* const* d_in, const int* in_sizes, int n_in,
                              void* d_out, int out_size, void* d_ws, size_t ws_size,
                              hipStream_t stream) {
    const float* query = (const float*)d_in[0];  // (4,512,512)
    const float* keys  = (const float*)d_in[1];  // (4,512,512)
    const float* W1    = (const float*)d_in[2];  // (128,512)
    const float* W2    = (const float*)d_in[3];  // (128,512)
    const float* v     = (const float*)d_in[4];  // (1,256)
    float* out = (float*)d_out;                  // (4,512,512) f32
    float* ws  = (float*)d_ws;                   // counter + 2048-float c'

    // zero the barrier counter (capture-safe; deterministic each call)
    hipMemsetAsync(d_ws, 0, 64, stream);
    fused_kernel<<<512, 256, 0, stream>>>(query, keys, W1, W2, v, ws, out);
}

// Round 5
// 29.219 us; speedup vs baseline: 1.5288x; 1.5288x over previous
//
#include <hip/hip_runtime.h>
#include <math.h>

// B=4, T=S=512, M=N=512, H=128
#define KDIM 512
#define HDIM 128
#define SDIM 512
#define TOTAL_ROWS 2048
#define INV_SCALE 0.04419417382415922f   // 1/sqrt(512)

// score[b,t,s] = a'[b,t] + c'[b,s]  (both pre-scaled)
//   a'[b,t] = inv_scale * sum_h v[h]   * tanh(q[b,t,:]·W2[h,:])
//   c'[b,s] = inv_scale * sum_h v[H+h] * tanh(k[b,s,:]·W1[h,:])

__device__ __forceinline__ float fast_tanh(float x) {
    // tanh(x) = 1 - 2/(e^{2x}+1); ~1e-7 abs error, graceful at +/-inf
    float e = __expf(2.0f * x);
    return 1.0f - 2.0f / (e + 1.0f);
}

// 512 blocks x 128 threads. blocks [0,256): query -> ws[0:2048]; [256,512): keys -> ws[2048:4096].
// Per block: 8 rows. Thread (ks = tid&7, hg = tid>>3): 8 rows x 8 h, K-split 8.
// Per thread: 4096 FMA, 128 ds_read_b128 (X), 128 global float4 (W, each W elem once/block).
__global__ __launch_bounds__(128, 1) void proj_kernel(
    const float* __restrict__ query, const float* __restrict__ keys,
    const float* __restrict__ W1, const float* __restrict__ W2,
    const float* __restrict__ v, float* __restrict__ ws)
{
    const int blk = blockIdx.x;
    const bool is_keys = (blk >= 256);
    const float* __restrict__ X  = is_keys ? keys : query;
    const float* __restrict__ W  = is_keys ? W1 : W2;
    const float* __restrict__ vv = v + (is_keys ? HDIM : 0);
    float* __restrict__ out = ws + (is_keys ? TOTAL_ROWS : 0);
    const int row0 = (is_keys ? blk - 256 : blk) * 8;

    __shared__ float sm_x[8][KDIM];   // 16 KB
    __shared__ float sm_p[2][8];      // per-wave partials

    const int tid = threadIdx.x;      // 0..127 (2 waves)
    const int ks  = tid & 7;          // K-split slot (lane bits 0-2)
    const int hg  = tid >> 3;         // h-group 0..15, 8 h each (lane bits 3-5 + wave bit)

    // Stage X tile: 8*512 floats = 1024 float4; 8 per thread, coalesced.
    {
        const float4* __restrict__ src = (const float4*)(X + (size_t)row0 * KDIM);
        float4* dst = (float4*)(&sm_x[0][0]);
        #pragma unroll
        for (int i = 0; i < 8; ++i) dst[tid + i * 128] = src[tid + i * 128];
    }
    __syncthreads();

    float acc[8][8];
    #pragma unroll
    for (int r = 0; r < 8; ++r)
        #pragma unroll
        for (int h = 0; h < 8; ++h) acc[r][h] = 0.0f;

    const float* __restrict__ wbase = W + (size_t)(hg * 8) * KDIM;

    // Thread covers K cols {jj*32 + ks*4 .. +3}, jj = 0..15.
    // Per jj: 8 W float4 (global/L2) + 8 X ds_read_b128 + 256 FMA.
    #pragma unroll 2
    for (int jj = 0; jj < 16; ++jj) {
        const int col = jj * 32 + ks * 4;
        float4 w[8];
        #pragma unroll
        for (int h = 0; h < 8; ++h)
            w[h] = *(const float4*)(wbase + h * KDIM + col);
        #pragma unroll
        for (int r = 0; r < 8; ++r) {
            const float4 x = *(const float4*)(&sm_x[r][col]);
            #pragma unroll
            for (int h = 0; h < 8; ++h) {
                acc[r][h] = fmaf(x.x, w[h].x, acc[r][h]);
                acc[r][h] = fmaf(x.y, w[h].y, acc[r][h]);
                acc[r][h] = fmaf(x.z, w[h].z, acc[r][h]);
                acc[r][h] = fmaf(x.w, w[h].w, acc[r][h]);
            }
        }
    }

    // K-split reduce over ks (lane bits 0-2): 64 accs x 3 levels.
    #pragma unroll
    for (int r = 0; r < 8; ++r)
        #pragma unroll
        for (int h = 0; h < 8; ++h) {
            float s = acc[r][h];
            s += __shfl_xor(s, 1, 64);
            s += __shfl_xor(s, 2, 64);
            s += __shfl_xor(s, 4, 64);
            acc[r][h] = s;
        }

    const float4 v0 = *(const float4*)(vv + hg * 8);
    const float4 v1 = *(const float4*)(vv + hg * 8 + 4);
    const int wave = tid >> 6;   // 0..1
    const int lane = tid & 63;

    #pragma unroll
    for (int r = 0; r < 8; ++r) {
        float rs = v0.x * fast_tanh(acc[r][0]) + v0.y * fast_tanh(acc[r][1])
                 + v0.z * fast_tanh(acc[r][2]) + v0.w * fast_tanh(acc[r][3])
                 + v1.x * fast_tanh(acc[r][4]) + v1.y * fast_tanh(acc[r][5])
                 + v1.z * fast_tanh(acc[r][6]) + v1.w * fast_tanh(acc[r][7]);
        // reduce over this wave's 8 h-groups (lane bits 3-5)
        rs += __shfl_xor(rs, 8, 64);
        rs += __shfl_xor(rs, 16, 64);
        rs += __shfl_xor(rs, 32, 64);
        if (lane == 0) sm_p[wave][r] = rs;
    }
    __syncthreads();

    if (tid < 8)
        out[row0 + tid] = (sm_p[0][tid] + sm_p[1][tid]) * INV_SCALE;
}

__global__ __launch_bounds__(128) void outer_kernel(
    const float* __restrict__ ws, float* __restrict__ out)
{
    // block = b*T + t; threads cover S=512 via float4
    const int bt = blockIdx.x;                  // 0..2047
    const float a = ws[bt];
    const int b = bt >> 9;                      // / T
    const float4* __restrict__ c4 = (const float4*)(ws + TOTAL_ROWS + (size_t)b * SDIM);

    const float4 cv = c4[threadIdx.x];
    float4 o;
    o.x = a + cv.x;
    o.y = a + cv.y;
    o.z = a + cv.z;
    o.w = a + cv.w;
    ((float4*)out)[(size_t)bt * (SDIM / 4) + threadIdx.x] = o;
}

extern "C" void kernel_launch(void* const* d_in, const int* in_sizes, int n_in,
                              void* d_out, int out_size, void* d_ws, size_t ws_size,
                              hipStream_t stream) {
    const float* query = (const float*)d_in[0];  // (4,512,512)
    const float* keys  = (const float*)d_in[1];  // (4,512,512)
    const float* W1    = (const float*)d_in[2];  // (128,512)
    const float* W2    = (const float*)d_in[3];  // (128,512)
    const float* v     = (const float*)d_in[4];  // (1,256)
    float* out = (float*)d_out;                  // (4,512,512) f32
    float* ws  = (float*)d_ws;                   // a' (2048) + c' (2048) floats

    proj_kernel<<<512, 128, 0, stream>>>(query, keys, W1, W2, v, ws);
    outer_kernel<<<TOTAL_ROWS, 128, 0, stream>>>(ws, out);
}

// Round 6
// 25.324 us; speedup vs baseline: 1.7639x; 1.1538x over previous
//
#include <hip/hip_runtime.h>
#include <math.h>

// B=4, T=S=512, M=N=512, H=128
#define KDIM 512
#define HDIM 128
#define SDIM 512
#define TOTAL_ROWS 2048
#define INV_SCALE 0.04419417382415922f   // 1/sqrt(512)

// score[b,t,s] = a'[b,t] + c'[b,s]  (both pre-scaled)
//   a'[b,t] = inv_scale * sum_h v[h]   * tanh(q[b,t,:]·W2[h,:])
//   c'[b,s] = inv_scale * sum_h v[H+h] * tanh(k[b,s,:]·W1[h,:])

__device__ __forceinline__ float fast_tanh(float x) {
    // tanh(x) = 1 - 2/(e^{2x}+1); ~1e-7 abs error, graceful at +/-inf
    float e = __expf(2.0f * x);
    return 1.0f - 2.0f / (e + 1.0f);
}

// 512 blocks x 256 threads (4 waves) -> 2 blocks/CU, 8 waves/CU, 2 waves/SIMD.
// blocks [0,256): query rows -> ws[0:2048]; [256,512): keys rows -> ws[2048:4096].
// 8 rows/block. Lane layout: ks = lane[0:2] (8 K-slots), kb = lane[3] (2 K-blocks),
// hgl = lane[4:5]; hg = wave*4 + hgl (16 h-groups x 8 h = 128).
// K-split 16 is entirely within the wave -> 4-level shfl reduce, no LDS combine.
// Per thread: 2048 FMA, 64 ds_read_b128 (X), 64 global float4 (W, once per block).
__global__ __launch_bounds__(256, 2) void proj_kernel(
    const float* __restrict__ query, const float* __restrict__ keys,
    const float* __restrict__ W1, const float* __restrict__ W2,
    const float* __restrict__ v, float* __restrict__ ws)
{
    const int blk = blockIdx.x;
    const bool is_keys = (blk >= 256);
    const float* __restrict__ X  = is_keys ? keys : query;
    const float* __restrict__ W  = is_keys ? W1 : W2;
    const float* __restrict__ vv = v + (is_keys ? HDIM : 0);
    float* __restrict__ out = ws + (is_keys ? TOTAL_ROWS : 0);
    const int row0 = (is_keys ? blk - 256 : blk) * 8;

    __shared__ float sm_x[8][KDIM];   // 16 KB
    __shared__ float sm_p[4][8];      // [wave][r] partials

    const int tid  = threadIdx.x;     // 0..255
    const int wave = tid >> 6;        // 0..3
    const int lane = tid & 63;
    const int ks   = lane & 7;
    const int kb   = (lane >> 3) & 1;
    const int hgl  = (lane >> 4) & 3;
    const int hg   = wave * 4 + hgl;  // 0..15

    // Stage X tile: 8*512 floats = 1024 float4; 4 per thread, coalesced.
    {
        const float4* __restrict__ src = (const float4*)(X + (size_t)row0 * KDIM);
        float4* dst = (float4*)(&sm_x[0][0]);
        #pragma unroll
        for (int i = 0; i < 4; ++i) dst[tid + i * 256] = src[tid + i * 256];
    }
    __syncthreads();

    float acc[8][8];
    #pragma unroll
    for (int r = 0; r < 8; ++r)
        #pragma unroll
        for (int h = 0; h < 8; ++h) acc[r][h] = 0.0f;

    const float* __restrict__ wbase = W + (size_t)(hg * 8) * KDIM;
    const int colbase = kb * 32 + ks * 4;

    // Thread covers K cols {jj*64 + kb*32 + ks*4 .. +3}, jj = 0..7 (32 of 512).
    // Per jj: 8 W float4 (coalesced, L2) + 8 X ds_read_b128 + 256 FMA.
    #pragma unroll 2
    for (int jj = 0; jj < 8; ++jj) {
        const int col = jj * 64 + colbase;
        float4 w[8];
        #pragma unroll
        for (int h = 0; h < 8; ++h)
            w[h] = *(const float4*)(wbase + h * KDIM + col);
        #pragma unroll
        for (int r = 0; r < 8; ++r) {
            const float4 x = *(const float4*)(&sm_x[r][col]);
            #pragma unroll
            for (int h = 0; h < 8; ++h) {
                acc[r][h] = fmaf(x.x, w[h].x, acc[r][h]);
                acc[r][h] = fmaf(x.y, w[h].y, acc[r][h]);
                acc[r][h] = fmaf(x.z, w[h].z, acc[r][h]);
                acc[r][h] = fmaf(x.w, w[h].w, acc[r][h]);
            }
        }
    }

    // K-split reduce over lane bits 0-3 (ks + kb): 64 accs x 4 levels, in-wave.
    #pragma unroll
    for (int r = 0; r < 8; ++r)
        #pragma unroll
        for (int h = 0; h < 8; ++h) {
            float s = acc[r][h];
            s += __shfl_xor(s, 1, 64);
            s += __shfl_xor(s, 2, 64);
            s += __shfl_xor(s, 4, 64);
            s += __shfl_xor(s, 8, 64);
            acc[r][h] = s;
        }

    const float4 v0 = *(const float4*)(vv + hg * 8);
    const float4 v1 = *(const float4*)(vv + hg * 8 + 4);

    #pragma unroll
    for (int r = 0; r < 8; ++r) {
        float rs = v0.x * fast_tanh(acc[r][0]) + v0.y * fast_tanh(acc[r][1])
                 + v0.z * fast_tanh(acc[r][2]) + v0.w * fast_tanh(acc[r][3])
                 + v1.x * fast_tanh(acc[r][4]) + v1.y * fast_tanh(acc[r][5])
                 + v1.z * fast_tanh(acc[r][6]) + v1.w * fast_tanh(acc[r][7]);
        // reduce over this wave's 4 h-groups (lane bits 4-5)
        rs += __shfl_xor(rs, 16, 64);
        rs += __shfl_xor(rs, 32, 64);
        if (lane == 0) sm_p[wave][r] = rs;
    }
    __syncthreads();

    if (tid < 8)
        out[row0 + tid] = (sm_p[0][tid] + sm_p[1][tid] + sm_p[2][tid] + sm_p[3][tid]) * INV_SCALE;
}

__global__ __launch_bounds__(128) void outer_kernel(
    const float* __restrict__ ws, float* __restrict__ out)
{
    // block = b*T + t; threads cover S=512 via float4
    const int bt = blockIdx.x;                  // 0..2047
    const float a = ws[bt];
    const int b = bt >> 9;                      // / T
    const float4* __restrict__ c4 = (const float4*)(ws + TOTAL_ROWS + (size_t)b * SDIM);

    const float4 cv = c4[threadIdx.x];
    float4 o;
    o.x = a + cv.x;
    o.y = a + cv.y;
    o.z = a + cv.z;
    o.w = a + cv.w;
    ((float4*)out)[(size_t)bt * (SDIM / 4) + threadIdx.x] = o;
}

extern "C" void kernel_launch(void* const* d_in, const int* in_sizes, int n_in,
                              void* d_out, int out_size, void* d_ws, size_t ws_size,
                              hipStream_t stream) {
    const float* query = (const float*)d_in[0];  // (4,512,512)
    const float* keys  = (const float*)d_in[1];  // (4,512,512)
    const float* W1    = (const float*)d_in[2];  // (128,512)
    const float* W2    = (const float*)d_in[3];  // (128,512)
    const float* v     = (const float*)d_in[4];  // (1,256)
    float* out = (float*)d_out;                  // (4,512,512) f32
    float* ws  = (float*)d_ws;                   // a' (2048) + c' (2048) floats

    proj_kernel<<<512, 256, 0, stream>>>(query, keys, W1, W2, v, ws);
    outer_kernel<<<TOTAL_ROWS, 128, 0, stream>>>(ws, out);
}